// Round 13
// baseline (6238.931 us; speedup 1.0000x reference)
//
#include <hip/hip_runtime.h>

#define BB 256
#define TT 2048
#define HD 100

typedef _Float16 f16x8 __attribute__((ext_vector_type(8)));
typedef float f32x4 __attribute__((ext_vector_type(4)));
typedef _Float16 h2v __attribute__((ext_vector_type(2)));

// LDS row strides in BYTES -- all odd multiples of 16 so consecutive rows land
// in different 16B bank groups (conflict-free ds_read_b128 across rows).
#define A1S 272   // A1: [16 rows][136 halfs]  k: 0..7 x | 8..107 h1 | pad
#define A2S 464   // A2: [16 rows][232 halfs]  k: 0..99 h1 | 100..199 h2 | pad
#define GSB 848   // G:  [16 rows][212 u32]    pair idx = type*52 + unit/2

__device__ __forceinline__ unsigned packh2(float a, float b) {
    h2v p; p[0] = (_Float16)a; p[1] = (_Float16)b;
    return __builtin_bit_cast(unsigned, p);
}
__device__ __forceinline__ float2 unp(unsigned u) {
    h2v p = __builtin_bit_cast(h2v, u);
    return make_float2((float)p[0], (float)p[1]);
}
__device__ __forceinline__ float rcp_f(float x) {
#if __has_builtin(__builtin_amdgcn_rcpf)
    return __builtin_amdgcn_rcpf(x);
#else
    return 1.0f / x;
#endif
}
#define LOG2E 1.4426950408889634f
__device__ __forceinline__ float tanh_f(float x) {
    return fmaf(2.0f, rcp_f(1.0f + exp2f(-2.0f * LOG2E * x)), -1.0f);
}
__device__ __forceinline__ f32x4 mfma16(uint4 a, uint4 b, f32x4 c) {
    return __builtin_amdgcn_mfma_f32_16x16x32_f16(
        __builtin_bit_cast(f16x8, a), __builtin_bit_cast(f16x8, b), c, 0, 0, 0);
}

// 16 blocks x 512 threads (8 waves). Block handles batch rows b0..b0+15.
// MFMA v_mfma_f32_16x16x32_f16: M=16 batch rows, N=16 gates/tile, 25 tiles/layer.
//   A frag: lane: row=l&15, k=(l>>4)*8+i (8 contiguous k) -> ds_read_b128 from A1/A2.
//   B frag: lane: col(gate)=l&15, k=(l>>4)*8+i -> REGISTERS (AGPR-resident, loaded once;
//           MFMA reads AGPRs directly -> no accvgpr-read tax, unlike the dot2 designs).
//   C frag: lane: col=l&15, row=(l>>4)*4+j (m89-verified).
// Tiles per wave: L1 {w,8+w,16+w} (+24 on wave5), L2 {w,8+w,16+w} (+24 on wave4)
// -> extra tiles on non-updater waves to balance registers.
// Per step: A(L1 mfma+act->G1) | b | B(update c1,h1->A1,A2 + x staging) | b |
//           C(L2 mfma+act->G2) | b | D(update c2,h2->A2).
// No v_readlane anywhere (no exec trap); MFMA phases run with FULL exec.
__global__ __launch_bounds__(512, 2) void lstm_mfma(
    const float* __restrict__ x,
    const float* __restrict__ w_ih1, const float* __restrict__ w_hh1,
    const float* __restrict__ b_ih1, const float* __restrict__ b_hh1,
    const float* __restrict__ w_ih2, const float* __restrict__ w_hh2,
    const float* __restrict__ b_ih2, const float* __restrict__ b_hh2,
    float* __restrict__ h2f)
{
    const int tid  = threadIdx.x;
    const int lane = tid & 63;
    const int w    = tid >> 6;          // wave 0..7
    const int b0   = blockIdx.x * 16;   // batch row base

    __shared__ __align__(16) _Float16 A1[16 * (A1S / 2)];
    __shared__ __align__(16) _Float16 A2[16 * (A2S / 2)];
    __shared__ __align__(16) unsigned G1[16 * (GSB / 4)];
    __shared__ __align__(16) unsigned G2[16 * (GSB / 4)];
    __shared__ unsigned XC[2][16][16][4];   // x chunks, f16x2-packed

    const int col = lane & 15, kg = lane >> 4;
    const int a1base = col * A1S + kg * 16;
    const int a2base = col * A2S + kg * 16;
    const int growb  = (kg * 4) * GSB;      // C row = kg*4 + j

    const int T1 = 3 + (w == 5);
    const int T2 = 3 + (w == 4);

    // ---------------- one-time B-fragment / constant loads ----------------
    uint4 b1[4][4];      // [tile][ktile]
    uint4 b2[4][7];
    float bias1v[4], am1[4], sc1[4], ad1[4]; int goff1[4];
    float bias2v[4], am2[4], sc2[4], ad2[4]; int goff2[4];

    #pragma unroll
    for (int ti = 0; ti < 4; ++ti) {
        if (ti < T1) {
            const int nn = (ti < 3) ? (ti * 8 + w) : 24;
            const int gate = nn * 16 + col;
            #pragma unroll
            for (int kt = 0; kt < 4; ++kt) {
                unsigned q[4];
                #pragma unroll
                for (int qq = 0; qq < 4; ++qq) {
                    const int ka = kt * 32 + kg * 8 + 2 * qq;
                    const int kb = ka + 1;
                    float va = (ka < 8) ? w_ih1[gate * 8 + ka]
                             : (ka < 108 ? w_hh1[(size_t)gate * HD + ka - 8] : 0.f);
                    float vb = (kb < 8) ? w_ih1[gate * 8 + kb]
                             : (kb < 108 ? w_hh1[(size_t)gate * HD + kb - 8] : 0.f);
                    q[qq] = packh2(va, vb);
                }
                b1[ti][kt] = make_uint4(q[0], q[1], q[2], q[3]);
            }
            bias1v[ti] = b_ih1[gate] + b_hh1[gate];
            const bool tg = (gate >= 200) && (gate < 300);
            am1[ti] = tg ? 2.f : 1.f;
            sc1[ti] = tg ? (-2.f * LOG2E) : (-LOG2E);
            ad1[ti] = tg ? -1.f : 0.f;
            const int type = gate / 100, u = gate - type * 100;
            goff1[ti] = (type * 52 + (u >> 1)) * 4 + (u & 1) * 2;
        }
        if (ti < T2) {
            const int nn = (ti < 3) ? (ti * 8 + w) : 24;
            const int gate = nn * 16 + col;
            #pragma unroll
            for (int kt = 0; kt < 7; ++kt) {
                unsigned q[4];
                #pragma unroll
                for (int qq = 0; qq < 4; ++qq) {
                    const int ka = kt * 32 + kg * 8 + 2 * qq;
                    const int kb = ka + 1;
                    float va = (ka < 100) ? w_ih2[(size_t)gate * HD + ka]
                             : (ka < 200 ? w_hh2[(size_t)gate * HD + ka - 100] : 0.f);
                    float vb = (kb < 100) ? w_ih2[(size_t)gate * HD + kb]
                             : (kb < 200 ? w_hh2[(size_t)gate * HD + kb - 100] : 0.f);
                    q[qq] = packh2(va, vb);
                }
                b2[ti][kt] = make_uint4(q[0], q[1], q[2], q[3]);
            }
            bias2v[ti] = b_ih2[gate] + b_hh2[gate];
            const bool tg = (gate >= 200) && (gate < 300);
            am2[ti] = tg ? 2.f : 1.f;
            sc2[ti] = tg ? (-2.f * LOG2E) : (-LOG2E);
            ad2[ti] = tg ? -1.f : 0.f;
            const int type = gate / 100, u = gate - type * 100;
            goff2[ti] = (type * 52 + (u >> 1)) * 4 + (u & 1) * 2;
        }
    }

    // updater role: thread t<208: row=t&15, units ub..ub+7 (u>=100 guarded off)
    const bool isUpd = tid < 208;
    const int  urow = tid & 15;
    const int  ub   = (tid >> 4) * 8;
    const int  gub  = urow * GSB + (ub >> 1) * 4;
    float c1a[8] = {0,0,0,0,0,0,0,0};
    float c2a[8] = {0,0,0,0,0,0,0,0};

    // ---------------- LDS init: zero A/G, stage x chunk 0 ----------------
    for (int i = tid; i < 16 * (A1S / 4); i += 512) ((unsigned*)A1)[i] = 0u;
    for (int i = tid; i < 16 * (A2S / 4); i += 512) ((unsigned*)A2)[i] = 0u;
    for (int i = tid; i < 16 * (GSB / 4); i += 512) { G1[i] = 0u; G2[i] = 0u; }
    {
        const int s = (tid >> 5) & 15, xr = (tid >> 1) & 15, hq = tid & 1;
        float4 v = *(const float4*)(x + ((size_t)(b0 + xr) * TT + s) * 8 + hq * 4);
        XC[0][s][xr][hq * 2]     = packh2(v.x, v.y);
        XC[0][s][xr][hq * 2 + 1] = packh2(v.z, v.w);
    }
    __syncthreads();
    if (tid < 64) {   // copy x[0] into A1 k0..7
        const int xr = tid >> 2, q = tid & 3;
        *(unsigned*)((char*)A1 + xr * A1S + q * 4) = XC[0][0][xr][q];
    }
    __syncthreads();

    // ---------------- main loop ----------------
    #pragma unroll 1
    for (int t = 0; t < TT; ++t) {
        // x chunk prefetch issue (latency hides under L1 MFMA)
        float4 xpf = {0.f, 0.f, 0.f, 0.f};
        const bool dopf = ((t & 15) == 14) && (t + 2 < TT);
        const int  pfc  = (t + 2) >> 4;
        const int  pfs = (tid >> 5) & 15, pfr = (tid >> 1) & 15, pfh = tid & 1;
        if (dopf)
            xpf = *(const float4*)(x + ((size_t)(b0 + pfr) * TT + (pfc * 16 + pfs)) * 8 + pfh * 4);

        // ========= phase A: L1 gates (MFMA, full exec) =========
        uint4 a1f[4];
        #pragma unroll
        for (int kt = 0; kt < 4; ++kt)
            a1f[kt] = *(const uint4*)((const char*)A1 + a1base + kt * 64);
        #pragma unroll
        for (int ti = 0; ti < 4; ++ti) if (ti < T1) {
            f32x4 acc = {0.f, 0.f, 0.f, 0.f};
            #pragma unroll
            for (int kt = 0; kt < 4; ++kt) acc = mfma16(a1f[kt], b1[ti][kt], acc);
            #pragma unroll
            for (int j = 0; j < 4; ++j) {
                float v = acc[j] + bias1v[ti];
                float a = fmaf(am1[ti], rcp_f(1.f + exp2f(sc1[ti] * v)), ad1[ti]);
                *(_Float16*)((char*)G1 + growb + j * GSB + goff1[ti]) = (_Float16)a;
            }
        }
        __syncthreads();

        // ========= phase B: L1 update + x staging =========
        if (isUpd) {
            const char* gp = (const char*)G1 + gub;
            uint4 pi = *(const uint4*)(gp);
            uint4 pf = *(const uint4*)(gp + 208);
            uint4 pg = *(const uint4*)(gp + 416);
            uint4 po = *(const uint4*)(gp + 624);
            unsigned ai[4] = {pi.x, pi.y, pi.z, pi.w};
            unsigned af[4] = {pf.x, pf.y, pf.z, pf.w};
            unsigned ag[4] = {pg.x, pg.y, pg.z, pg.w};
            unsigned ao[4] = {po.x, po.y, po.z, po.w};
            #pragma unroll
            for (int q = 0; q < 4; ++q) {
                const int u0 = ub + 2 * q;
                float2 vi = unp(ai[q]), vf = unp(af[q]), vg = unp(ag[q]), vo = unp(ao[q]);
                c1a[2*q]   = vf.x * c1a[2*q]   + vi.x * vg.x;
                c1a[2*q+1] = vf.y * c1a[2*q+1] + vi.y * vg.y;
                float h0 = vo.x * tanh_f(c1a[2*q]);
                float h1 = vo.y * tanh_f(c1a[2*q+1]);
                if (u0 < 100) {
                    unsigned hp = packh2(h0, h1);
                    *(unsigned*)((char*)A1 + urow * A1S + 16 + u0 * 2) = hp;   // k = 8+u
                    *(unsigned*)((char*)A2 + urow * A2S + u0 * 2)      = hp;   // k = u
                }
            }
        }
        if (dopf) {
            XC[pfc & 1][pfs][pfr][pfh * 2]     = packh2(xpf.x, xpf.y);
            XC[pfc & 1][pfs][pfr][pfh * 2 + 1] = packh2(xpf.z, xpf.w);
        }
        {
            const int nt = t + 1;
            if (nt < TT && tid < 64) {
                const int xr = tid >> 2, q = tid & 3;
                *(unsigned*)((char*)A1 + xr * A1S + q * 4) = XC[(nt >> 4) & 1][nt & 15][xr][q];
            }
        }
        __syncthreads();

        // ========= phase C: L2 gates (MFMA, full exec) =========
        uint4 a2f[7];
        #pragma unroll
        for (int kt = 0; kt < 7; ++kt)
            a2f[kt] = *(const uint4*)((const char*)A2 + a2base + kt * 64);
        #pragma unroll
        for (int ti = 0; ti < 4; ++ti) if (ti < T2) {
            f32x4 acc = {0.f, 0.f, 0.f, 0.f};
            #pragma unroll
            for (int kt = 0; kt < 7; ++kt) acc = mfma16(a2f[kt], b2[ti][kt], acc);
            #pragma unroll
            for (int j = 0; j < 4; ++j) {
                float v = acc[j] + bias2v[ti];
                float a = fmaf(am2[ti], rcp_f(1.f + exp2f(sc2[ti] * v)), ad2[ti]);
                *(_Float16*)((char*)G2 + growb + j * GSB + goff2[ti]) = (_Float16)a;
            }
        }
        __syncthreads();

        // ========= phase D: L2 update =========
        if (isUpd) {
            const char* gp = (const char*)G2 + gub;
            uint4 pi = *(const uint4*)(gp);
            uint4 pf = *(const uint4*)(gp + 208);
            uint4 pg = *(const uint4*)(gp + 416);
            uint4 po = *(const uint4*)(gp + 624);
            unsigned ai[4] = {pi.x, pi.y, pi.z, pi.w};
            unsigned af[4] = {pf.x, pf.y, pf.z, pf.w};
            unsigned ag[4] = {pg.x, pg.y, pg.z, pg.w};
            unsigned ao[4] = {po.x, po.y, po.z, po.w};
            #pragma unroll
            for (int q = 0; q < 4; ++q) {
                const int u0 = ub + 2 * q;
                float2 vi = unp(ai[q]), vf = unp(af[q]), vg = unp(ag[q]), vo = unp(ao[q]);
                c2a[2*q]   = vf.x * c2a[2*q]   + vi.x * vg.x;
                c2a[2*q+1] = vf.y * c2a[2*q+1] + vi.y * vg.y;
                float h0 = vo.x * tanh_f(c2a[2*q]);
                float h1 = vo.y * tanh_f(c2a[2*q+1]);
                if (u0 < 100) {
                    *(unsigned*)((char*)A2 + urow * A2S + 200 + u0 * 2) = packh2(h0, h1); // k=100+u
                    if (t == TT - 1) {
                        h2f[(size_t)(b0 + urow) * HD + u0]     = h0;
                        h2f[(size_t)(b0 + urow) * HD + u0 + 1] = h1;
                    }
                }
            }
        }
        // no barrier needed: next phase A touches only A1/G1; b1(t+1) orders the rest
    }
}

// ---------------- FC head ----------------
__global__ void fc_head(const float* __restrict__ h2,
                        const float* __restrict__ fc1_w, const float* __restrict__ fc1_b,
                        const float* __restrict__ fc2_w, const float* __restrict__ fc2_b,
                        float* __restrict__ out)
{
    const int bidx = threadIdx.x;
    const float* h = h2 + (size_t)bidx * HD;
    float hv[HD];
    #pragma unroll
    for (int kk = 0; kk < HD / 4; ++kk) {
        float4 v = *(const float4*)(h + 4 * kk);
        hv[4*kk+0] = v.x; hv[4*kk+1] = v.y; hv[4*kk+2] = v.z; hv[4*kk+3] = v.w;
    }
    float y = fc2_b[0];
    #pragma unroll
    for (int m = 0; m < 25; ++m) {
        float a = fc1_b[m];
        const float* wp = fc1_w + m * HD;
        #pragma unroll
        for (int k = 0; k < HD; ++k) a += hv[k] * wp[k];
        y += a * fc2_w[m];
    }
    out[bidx] = y;
}

extern "C" void kernel_launch(void* const* d_in, const int* in_sizes, int n_in,
                              void* d_out, int out_size, void* d_ws, size_t ws_size,
                              hipStream_t stream) {
    const float* x     = (const float*)d_in[0];
    const float* w_ih1 = (const float*)d_in[1];
    const float* w_hh1 = (const float*)d_in[2];
    const float* b_ih1 = (const float*)d_in[3];
    const float* b_hh1 = (const float*)d_in[4];
    const float* w_ih2 = (const float*)d_in[5];
    const float* w_hh2 = (const float*)d_in[6];
    const float* b_ih2 = (const float*)d_in[7];
    const float* b_hh2 = (const float*)d_in[8];
    const float* fc1_w = (const float*)d_in[9];
    const float* fc1_b = (const float*)d_in[10];
    const float* fc2_w = (const float*)d_in[11];
    const float* fc2_b = (const float*)d_in[12];
    float* out = (float*)d_out;

    float* h2f = (float*)d_ws;   // [BB][HD] f32

    lstm_mfma<<<16, 512, 0, stream>>>(x, w_ih1, w_hh1, b_ih1, b_hh1,
                                      w_ih2, w_hh2, b_ih2, b_hh2, h2f);
    fc_head<<<1, 256, 0, stream>>>(h2f, fc1_w, fc1_b, fc2_w, fc2_b, out);
}

// Round 14
// 4073.519 us; speedup vs baseline: 1.5316x; 1.5316x over previous
//
#include <hip/hip_runtime.h>

#define BB 256
#define TT 2048
#define HD 100

typedef _Float16 f16x8 __attribute__((ext_vector_type(8)));
typedef float f32x4 __attribute__((ext_vector_type(4)));
typedef _Float16 h2v __attribute__((ext_vector_type(2)));

// LDS row strides in BYTES (odd multiples of 16 -> dense 2-pass b128 reads)
#define A1S 272   // A1: [16 rows][136 halfs]  k: 0..7 x | 8..107 h1 | pad
#define A2S 464   // A2: [16 rows][232 halfs]  k: 0..99 h1 | 100..199 h2 | pad
#define GSB 848   // G:  [16 rows][212 u32]    pair slot = type*52 + unit/2

__device__ __forceinline__ unsigned packh2(float a, float b) {
    h2v p; p[0] = (_Float16)a; p[1] = (_Float16)b;
    return __builtin_bit_cast(unsigned, p);
}
__device__ __forceinline__ float2 unp(unsigned u) {
    h2v p = __builtin_bit_cast(h2v, u);
    return make_float2((float)p[0], (float)p[1]);
}
__device__ __forceinline__ float rcp_f(float x) {
#if __has_builtin(__builtin_amdgcn_rcpf)
    return __builtin_amdgcn_rcpf(x);
#else
    return 1.0f / x;
#endif
}
#define LOG2E 1.4426950408889634f
__device__ __forceinline__ float tanh_f(float x) {
    return fmaf(2.0f, rcp_f(1.0f + exp2f(-2.0f * LOG2E * x)), -1.0f);
}
__device__ __forceinline__ f32x4 mfma16(uint4 a, uint4 b, f32x4 c) {
    return __builtin_amdgcn_mfma_f32_16x16x32_f16(
        __builtin_bit_cast(f16x8, a), __builtin_bit_cast(f16x8, b), c, 0, 0, 0);
}

// Chunk-pipelined MFMA LSTM. One launch per chunk; grid 32 x 512 threads.
//   blocks 0..15  (role 0): LAYER 1 on chunk ch    (batch rows blk*16..+15)
//   blocks 16..31 (role 1): LAYER 2 on chunk ch-1
// Splitting the layers across blocks keeps each role's MFMA B-fragments
// (L1: 16 uint4, L2: 28 uint4) within the unified register budget -- R13 held
// both sets in one kernel (176+ regs) and spilled to scratch (the 6.2ms).
// B-fragments are MFMA-only operands: AGPR residency is free (MFMA reads
// AGPRs directly). All fragment layouts verbatim from R13 (correctness-
// verified: passed with absmax 4.9e-4).
// h1 crosses layers through double-buffered h1buf in d_ws; launch-boundary
// ordering makes producer->consumer safe (R12-verified).
__global__ __launch_bounds__(512, 1) void lstm_mfma_pipe(
    const float* __restrict__ x,
    const float* __restrict__ w_ih1, const float* __restrict__ w_hh1,
    const float* __restrict__ b_ih1, const float* __restrict__ b_hh1,
    const float* __restrict__ w_ih2, const float* __restrict__ w_hh2,
    const float* __restrict__ b_ih2, const float* __restrict__ b_hh2,
    unsigned* __restrict__ h1buf,   // [2][Tc][BB][50] packed f16x2
    float* __restrict__ c1s,        // [BB][HD]
    unsigned* __restrict__ h2sp,    // [BB][50] packed h2 state
    float* __restrict__ c2s,        // [BB][HD]
    float* __restrict__ h2f,        // [BB][HD] final h2 (f32)
    int Tc, int ch, int nch)
{
    const int role = blockIdx.x >> 4;
    const int b0   = (blockIdx.x & 15) * 16;
    const int tid  = threadIdx.x;
    const int lane = tid & 63;
    const int w    = tid >> 6;

    __shared__ __align__(16) _Float16 A1[16 * (A1S / 2)];
    __shared__ __align__(16) _Float16 A2[16 * (A2S / 2)];
    __shared__ __align__(16) unsigned G[16 * (GSB / 4)];
    __shared__ unsigned XC[2][16][16][4];

    const int col = lane & 15, kg = lane >> 4;
    const int growb = (kg * 4) * GSB;       // C row = kg*4 + j

    const bool isUpd = tid < 208;
    const int  urow = tid & 15;
    const int  ub   = (tid >> 4) * 8;       // units ub..ub+7 (clipped at 100)
    const int  gub  = urow * GSB + (ub >> 1) * 4;

    if (role == 0) {
        // ======================= LAYER 1, chunk ch =======================
        if (ch >= nch) return;
        const int t0 = ch * Tc, first = (ch == 0);
        const size_t bufC = (size_t)(ch & 1) * Tc * BB * 50;
        const size_t bufP = (size_t)((ch ^ 1) & 1) * Tc * BB * 50;
        const int a1base = col * A1S + kg * 16;
        const int T1 = 3 + (w == 5);

        uint4 b1[4][4];
        float bias1v[4], am1[4], sc1[4], ad1[4]; int goff1[4];
        #pragma unroll
        for (int ti = 0; ti < 4; ++ti) if (ti < T1) {
            const int nn = (ti < 3) ? (ti * 8 + w) : 24;
            const int gate = nn * 16 + col;
            #pragma unroll
            for (int kt = 0; kt < 4; ++kt) {
                unsigned q[4];
                #pragma unroll
                for (int qq = 0; qq < 4; ++qq) {
                    const int ka = kt * 32 + kg * 8 + 2 * qq, kb = ka + 1;
                    float va = (ka < 8) ? w_ih1[gate * 8 + ka]
                             : (ka < 108 ? w_hh1[(size_t)gate * HD + ka - 8] : 0.f);
                    float vb = (kb < 8) ? w_ih1[gate * 8 + kb]
                             : (kb < 108 ? w_hh1[(size_t)gate * HD + kb - 8] : 0.f);
                    q[qq] = packh2(va, vb);
                }
                b1[ti][kt] = make_uint4(q[0], q[1], q[2], q[3]);
            }
            bias1v[ti] = b_ih1[gate] + b_hh1[gate];
            const bool tg = (gate >= 200) && (gate < 300);
            am1[ti] = tg ? 2.f : 1.f;
            sc1[ti] = tg ? (-2.f * LOG2E) : (-LOG2E);
            ad1[ti] = tg ? -1.f : 0.f;
            const int type = gate / 100, u = gate - type * 100;
            goff1[ti] = (type * 52 + (u >> 1)) * 4 + (u & 1) * 2;
        }

        float c1a[8] = {0,0,0,0,0,0,0,0};
        if (isUpd && !first) {
            #pragma unroll
            for (int q = 0; q < 4; ++q) {
                const int u0 = ub + 2 * q;
                if (u0 < 100) {
                    c1a[2*q]   = c1s[(b0 + urow) * HD + u0];
                    c1a[2*q+1] = c1s[(b0 + urow) * HD + u0 + 1];
                }
            }
        }

        for (int i = tid; i < 16 * (A1S / 4); i += 512) ((unsigned*)A1)[i] = 0u;
        for (int i = tid; i < 16 * (GSB / 4); i += 512) G[i] = 0u;
        if (!first) {   // stage prev-chunk last h1 into A1 k8..107
            for (int i = tid; i < 800; i += 512) {
                const int row = i / 50, pr = i - row * 50;
                unsigned hp = h1buf[bufP + ((size_t)(Tc - 1) * BB + b0 + row) * 50 + pr];
                *(unsigned*)((char*)A1 + row * A1S + 16 + pr * 4) = hp;
            }
        }
        {   // stage x chunk 0
            const int s = (tid >> 5) & 15, xr = (tid >> 1) & 15, hq = tid & 1;
            float4 v = *(const float4*)(x + ((size_t)(b0 + xr) * TT + t0 + s) * 8 + hq * 4);
            XC[0][s][xr][hq * 2]     = packh2(v.x, v.y);
            XC[0][s][xr][hq * 2 + 1] = packh2(v.z, v.w);
        }
        __syncthreads();
        if (tid < 64) {     // x(t=0) -> A1 k0..7
            const int xr = tid >> 2, q = tid & 3;
            *(unsigned*)((char*)A1 + xr * A1S + q * 4) = XC[0][0][xr][q];
        }
        __syncthreads();

        #pragma unroll 1
        for (int t = 0; t < Tc; ++t) {
            float4 xpf = {0.f, 0.f, 0.f, 0.f};
            const bool dopf = ((t & 15) == 14) && (t + 2 < Tc);
            const int  pfc = (t + 2) >> 4;
            const int  pfs = (tid >> 5) & 15, pfr = (tid >> 1) & 15, pfh = tid & 1;
            if (dopf)
                xpf = *(const float4*)(x + ((size_t)(b0 + pfr) * TT + t0 + pfc * 16 + pfs) * 8 + pfh * 4);

            // phase A: MFMA gates -> act -> G
            uint4 a1f[4];
            #pragma unroll
            for (int kt = 0; kt < 4; ++kt)
                a1f[kt] = *(const uint4*)((const char*)A1 + a1base + kt * 64);
            #pragma unroll
            for (int ti = 0; ti < 4; ++ti) if (ti < T1) {
                f32x4 acc = {0.f, 0.f, 0.f, 0.f};
                #pragma unroll
                for (int kt = 0; kt < 4; ++kt) acc = mfma16(a1f[kt], b1[ti][kt], acc);
                #pragma unroll
                for (int j = 0; j < 4; ++j) {
                    float v = acc[j] + bias1v[ti];
                    float a = fmaf(am1[ti], rcp_f(1.f + exp2f(sc1[ti] * v)), ad1[ti]);
                    *(_Float16*)((char*)G + growb + j * GSB + goff1[ti]) = (_Float16)a;
                }
            }
            __syncthreads();

            // phase B: update c1/h1 -> A1 + h1buf; x staging
            if (isUpd) {
                const char* gp = (const char*)G + gub;
                uint4 pi = *(const uint4*)(gp);
                uint4 pf = *(const uint4*)(gp + 208);
                uint4 pg = *(const uint4*)(gp + 416);
                uint4 po = *(const uint4*)(gp + 624);
                unsigned ai[4] = {pi.x, pi.y, pi.z, pi.w};
                unsigned af[4] = {pf.x, pf.y, pf.z, pf.w};
                unsigned ag[4] = {pg.x, pg.y, pg.z, pg.w};
                unsigned ao[4] = {po.x, po.y, po.z, po.w};
                #pragma unroll
                for (int q = 0; q < 4; ++q) {
                    const int u0 = ub + 2 * q;
                    float2 vi = unp(ai[q]), vf = unp(af[q]), vg = unp(ag[q]), vo = unp(ao[q]);
                    c1a[2*q]   = vf.x * c1a[2*q]   + vi.x * vg.x;
                    c1a[2*q+1] = vf.y * c1a[2*q+1] + vi.y * vg.y;
                    float h0 = vo.x * tanh_f(c1a[2*q]);
                    float h1 = vo.y * tanh_f(c1a[2*q+1]);
                    if (u0 < 100) {
                        unsigned hp = packh2(h0, h1);
                        *(unsigned*)((char*)A1 + urow * A1S + 16 + u0 * 2) = hp;
                        h1buf[bufC + ((size_t)t * BB + b0 + urow) * 50 + (ub >> 1) + q] = hp;
                        if (t == Tc - 1) {
                            c1s[(b0 + urow) * HD + u0]     = c1a[2*q];
                            c1s[(b0 + urow) * HD + u0 + 1] = c1a[2*q+1];
                        }
                    }
                }
            }
            if (dopf) {
                XC[pfc & 1][pfs][pfr][pfh * 2]     = packh2(xpf.x, xpf.y);
                XC[pfc & 1][pfs][pfr][pfh * 2 + 1] = packh2(xpf.z, xpf.w);
            }
            {
                const int nt = t + 1;
                if (nt < Tc && tid < 64) {
                    const int xr = tid >> 2, q = tid & 3;
                    *(unsigned*)((char*)A1 + xr * A1S + q * 4) = XC[(nt >> 4) & 1][nt & 15][xr][q];
                }
            }
            __syncthreads();
        }
    } else {
        // ======================= LAYER 2, chunk ch-1 =======================
        if (ch < 1) return;
        const int first = (ch == 1), last = (ch == nch);
        const unsigned* h1rd = h1buf + (size_t)((ch - 1) & 1) * Tc * BB * 50;
        const int a2base = col * A2S + kg * 16;
        const int T2 = 3 + (w == 4);

        uint4 b2[4][7];
        float bias2v[4], am2[4], sc2[4], ad2[4]; int goff2[4];
        #pragma unroll
        for (int ti = 0; ti < 4; ++ti) if (ti < T2) {
            const int nn = (ti < 3) ? (ti * 8 + w) : 24;
            const int gate = nn * 16 + col;
            #pragma unroll
            for (int kt = 0; kt < 7; ++kt) {
                unsigned q[4];
                #pragma unroll
                for (int qq = 0; qq < 4; ++qq) {
                    const int ka = kt * 32 + kg * 8 + 2 * qq, kb = ka + 1;
                    float va = (ka < 100) ? w_ih2[(size_t)gate * HD + ka]
                             : (ka < 200 ? w_hh2[(size_t)gate * HD + ka - 100] : 0.f);
                    float vb = (kb < 100) ? w_ih2[(size_t)gate * HD + kb]
                             : (kb < 200 ? w_hh2[(size_t)gate * HD + kb - 100] : 0.f);
                    q[qq] = packh2(va, vb);
                }
                b2[ti][kt] = make_uint4(q[0], q[1], q[2], q[3]);
            }
            bias2v[ti] = b_ih2[gate] + b_hh2[gate];
            const bool tg = (gate >= 200) && (gate < 300);
            am2[ti] = tg ? 2.f : 1.f;
            sc2[ti] = tg ? (-2.f * LOG2E) : (-LOG2E);
            ad2[ti] = tg ? -1.f : 0.f;
            const int type = gate / 100, u = gate - type * 100;
            goff2[ti] = (type * 52 + (u >> 1)) * 4 + (u & 1) * 2;
        }

        float c2a[8] = {0,0,0,0,0,0,0,0};
        if (isUpd && !first) {
            #pragma unroll
            for (int q = 0; q < 4; ++q) {
                const int u0 = ub + 2 * q;
                if (u0 < 100) {
                    c2a[2*q]   = c2s[(b0 + urow) * HD + u0];
                    c2a[2*q+1] = c2s[(b0 + urow) * HD + u0 + 1];
                }
            }
        }

        for (int i = tid; i < 16 * (A2S / 4); i += 512) ((unsigned*)A2)[i] = 0u;
        for (int i = tid; i < 16 * (GSB / 4); i += 512) G[i] = 0u;
        for (int i = tid; i < 800; i += 512) {      // h1(step 0) -> A2 k0..99
            const int row = i / 50, pr = i - row * 50;
            *(unsigned*)((char*)A2 + row * A2S + pr * 4) =
                h1rd[((size_t)0 * BB + b0 + row) * 50 + pr];
        }
        if (!first) {                               // h2 prev state -> A2 k100..199
            for (int i = tid; i < 800; i += 512) {
                const int row = i / 50, pr = i - row * 50;
                *(unsigned*)((char*)A2 + row * A2S + 200 + pr * 4) =
                    h2sp[(size_t)(b0 + row) * 50 + pr];
            }
        }
        // per-thread h1-prefetch slots (loop-invariant mapping)
        const int i0 = tid, i1 = tid + 512;
        const int r0 = i0 / 50, pr0 = i0 - r0 * 50;
        const int r1 = (i1 < 800) ? i1 / 50 : 0, pr1 = (i1 < 800) ? (i1 - (i1 / 50) * 50) : 0;
        const bool v1 = (i1 < 800);
        __syncthreads();

        #pragma unroll 1
        for (int t = 0; t < Tc; ++t) {
            // issue next-step h1 loads (hidden under MFMA)
            const int tn = (t + 1 < Tc) ? (t + 1) : t;
            unsigned p0 = h1rd[((size_t)tn * BB + b0 + r0) * 50 + pr0];
            unsigned p1 = v1 ? h1rd[((size_t)tn * BB + b0 + r1) * 50 + pr1] : 0u;

            // phase C: MFMA gates -> act -> G
            uint4 a2f[7];
            #pragma unroll
            for (int kt = 0; kt < 7; ++kt)
                a2f[kt] = *(const uint4*)((const char*)A2 + a2base + kt * 64);
            #pragma unroll
            for (int ti = 0; ti < 4; ++ti) if (ti < T2) {
                f32x4 acc = {0.f, 0.f, 0.f, 0.f};
                #pragma unroll
                for (int kt = 0; kt < 7; ++kt) acc = mfma16(a2f[kt], b2[ti][kt], acc);
                #pragma unroll
                for (int j = 0; j < 4; ++j) {
                    float v = acc[j] + bias2v[ti];
                    float a = fmaf(am2[ti], rcp_f(1.f + exp2f(sc2[ti] * v)), ad2[ti]);
                    *(_Float16*)((char*)G + growb + j * GSB + goff2[ti]) = (_Float16)a;
                }
            }
            __syncthreads();

            // phase D: update c2/h2 -> A2 k100..; write prefetched h1 -> A2 k0..
            if (isUpd) {
                const char* gp = (const char*)G + gub;
                uint4 pi = *(const uint4*)(gp);
                uint4 pf = *(const uint4*)(gp + 208);
                uint4 pg = *(const uint4*)(gp + 416);
                uint4 po = *(const uint4*)(gp + 624);
                unsigned ai[4] = {pi.x, pi.y, pi.z, pi.w};
                unsigned af[4] = {pf.x, pf.y, pf.z, pf.w};
                unsigned ag[4] = {pg.x, pg.y, pg.z, pg.w};
                unsigned ao[4] = {po.x, po.y, po.z, po.w};
                #pragma unroll
                for (int q = 0; q < 4; ++q) {
                    const int u0 = ub + 2 * q;
                    float2 vi = unp(ai[q]), vf = unp(af[q]), vg = unp(ag[q]), vo = unp(ao[q]);
                    c2a[2*q]   = vf.x * c2a[2*q]   + vi.x * vg.x;
                    c2a[2*q+1] = vf.y * c2a[2*q+1] + vi.y * vg.y;
                    float h0 = vo.x * tanh_f(c2a[2*q]);
                    float h1 = vo.y * tanh_f(c2a[2*q+1]);
                    if (u0 < 100) {
                        unsigned hp = packh2(h0, h1);
                        *(unsigned*)((char*)A2 + urow * A2S + 200 + u0 * 2) = hp;
                        if (t == Tc - 1) {
                            h2sp[(size_t)(b0 + urow) * 50 + (ub >> 1) + q] = hp;
                            c2s[(b0 + urow) * HD + u0]     = c2a[2*q];
                            c2s[(b0 + urow) * HD + u0 + 1] = c2a[2*q+1];
                            if (last) {
                                h2f[(size_t)(b0 + urow) * HD + u0]     = h0;
                                h2f[(size_t)(b0 + urow) * HD + u0 + 1] = h1;
                            }
                        }
                    }
                }
            }
            *(unsigned*)((char*)A2 + r0 * A2S + pr0 * 4) = p0;
            if (v1) *(unsigned*)((char*)A2 + r1 * A2S + pr1 * 4) = p1;
            __syncthreads();
        }
    }
}

// ---------------- FC head ----------------
__global__ void fc_head(const float* __restrict__ h2,
                        const float* __restrict__ fc1_w, const float* __restrict__ fc1_b,
                        const float* __restrict__ fc2_w, const float* __restrict__ fc2_b,
                        float* __restrict__ out)
{
    const int bidx = threadIdx.x;
    const float* h = h2 + (size_t)bidx * HD;
    float hv[HD];
    #pragma unroll
    for (int kk = 0; kk < HD / 4; ++kk) {
        float4 v = *(const float4*)(h + 4 * kk);
        hv[4*kk+0] = v.x; hv[4*kk+1] = v.y; hv[4*kk+2] = v.z; hv[4*kk+3] = v.w;
    }
    float y = fc2_b[0];
    #pragma unroll
    for (int m = 0; m < 25; ++m) {
        float a = fc1_b[m];
        const float* wp = fc1_w + m * HD;
        #pragma unroll
        for (int k = 0; k < HD; ++k) a += hv[k] * wp[k];
        y += a * fc2_w[m];
    }
    out[bidx] = y;
}

extern "C" void kernel_launch(void* const* d_in, const int* in_sizes, int n_in,
                              void* d_out, int out_size, void* d_ws, size_t ws_size,
                              hipStream_t stream) {
    const float* x     = (const float*)d_in[0];
    const float* w_ih1 = (const float*)d_in[1];
    const float* w_hh1 = (const float*)d_in[2];
    const float* b_ih1 = (const float*)d_in[3];
    const float* b_hh1 = (const float*)d_in[4];
    const float* w_ih2 = (const float*)d_in[5];
    const float* w_hh2 = (const float*)d_in[6];
    const float* b_ih2 = (const float*)d_in[7];
    const float* b_hh2 = (const float*)d_in[8];
    const float* fc1_w = (const float*)d_in[9];
    const float* fc1_b = (const float*)d_in[10];
    const float* fc2_w = (const float*)d_in[11];
    const float* fc2_b = (const float*)d_in[12];
    float* out = (float*)d_out;

    int Tc = 256;  // multiple of 16, divides TT
    while (Tc > 32 &&
           2 * (size_t)Tc * BB * 50 * 4 + (size_t)BB * (HD * 3 + 50) * 4 > ws_size)
        Tc >>= 1;
    const int nch = TT / Tc;

    unsigned* h1buf = (unsigned*)d_ws;                      // [2][Tc][BB][50]
    float* c1s = (float*)(h1buf + 2 * (size_t)Tc * BB * 50);
    float* c2s = c1s + (size_t)BB * HD;
    float* h2f = c2s + (size_t)BB * HD;
    unsigned* h2sp = (unsigned*)(h2f + (size_t)BB * HD);

    for (int ch = 0; ch <= nch; ++ch) {
        lstm_mfma_pipe<<<32, 512, 0, stream>>>(x, w_ih1, w_hh1, b_ih1, b_hh1,
                                               w_ih2, w_hh2, b_ih2, b_hh2,
                                               h1buf, c1s, h2sp, c2s, h2f,
                                               Tc, ch, nch);
    }
    fc_head<<<1, 256, 0, stream>>>(h2f, fc1_w, fc1_b, fc2_w, fc2_b, out);
}